// Round 19
// baseline (81.137 us; speedup 1.0000x reference)
//
#include <hip/hip_runtime.h>
#include <hip/hip_bf16.h>
#include <hip/hip_fp16.h>
#include <math.h>
#include <string.h>

typedef _Float16 half8 __attribute__((ext_vector_type(8)));
typedef _Float16 half4 __attribute__((ext_vector_type(4)));
typedef float floatx4 __attribute__((ext_vector_type(4)));
typedef float floatx16 __attribute__((ext_vector_type(16)));

#if defined(__has_builtin) && __has_builtin(__builtin_amdgcn_mfma_f32_16x16x16f16)
#define MFMA_PV(a, b, c) __builtin_amdgcn_mfma_f32_16x16x16f16((a), (b), (c), 0, 0, 0)
#else
__device__ __forceinline__ floatx4 mfma_pv_asm(half4 a, half4 b, floatx4 c) {
  floatx4 d;
  asm volatile("v_mfma_f32_16x16x16_f16 %0, %1, %2, %3"
               : "=v"(d) : "v"(a), "v"(b), "v"(c));
  return d;
}
#define MFMA_PV(a, b, c) mfma_pv_asm((a), (b), (c))
#endif

__device__ __forceinline__ floatx16 MFMA_S1(half4 a, half4 b, floatx16 c) {
#if defined(__has_builtin) && __has_builtin(__builtin_amdgcn_mfma_f32_32x32x8f16)
  return __builtin_amdgcn_mfma_f32_32x32x8f16(a, b, c, 0, 0, 0);
#else
  floatx16 d;
  asm volatile("v_mfma_f32_32x32x8_f16 %0, %1, %2, %3"
               : "=v"(d) : "v"(a), "v"(b), "v"(c));
  return d;
#endif
}

__device__ __forceinline__ floatx16 MFMA_S2(half8 a, half8 b, floatx16 c) {
#if defined(__has_builtin) && __has_builtin(__builtin_amdgcn_mfma_f32_32x32x16_f16)
  return __builtin_amdgcn_mfma_f32_32x32x16_f16(a, b, c, 0, 0, 0);
#else
  floatx16 d;
  asm volatile("v_mfma_f32_32x32x16_f16 %0, %1, %2, %3"
               : "=v"(d) : "v"(a), "v"(b), "v"(c));
  return d;
#endif
}

__device__ __forceinline__ float gelu_exact(float z) {
  return 0.5f * z * (1.0f + erff(z * 0.70710678118654752f));
}
__device__ __forceinline__ unsigned int packh2(float a, float b) {
  __half2 h = __halves2half2(__float2half_rn(a), __float2half_rn(b));
  unsigned int u;
  memcpy(&u, &h, 4);
  return u;
}

// ---------------------------------------------------------------------------
// Fused prep (R11-proven): bx<2048 -> LayerNorm row (f16 out); else weight
// transpose, GELU half2{g0,dg} lerp table, and MFMA weight fragments.
// ---------------------------------------------------------------------------
__global__ __launch_bounds__(256) void prep_kernel(
    const float* __restrict__ x, const float* __restrict__ g,
    const float* __restrict__ bv, __half* __restrict__ h16,
    const float* __restrict__ w_qkv, const float* __restrict__ w_o,
    const float* __restrict__ w1, const float* __restrict__ b1,
    const float* __restrict__ w2,
    __half* __restrict__ wqT, __half* __restrict__ woT,
    unsigned int* __restrict__ gtabu, uint2* __restrict__ A1g,
    uint4* __restrict__ A2g) {
  int t = threadIdx.x;
  if (blockIdx.x < 2048) {
    int row = blockIdx.x;
    float v = x[(size_t)row * 256 + t];
    float s = v, q = v * v;
#pragma unroll
    for (int o = 32; o > 0; o >>= 1) {
      s += __shfl_xor(s, o);
      q += __shfl_xor(q, o);
    }
    __shared__ float ss[4], qq[4];
    int w = t >> 6, l = t & 63;
    if (l == 0) { ss[w] = s; qq[w] = q; }
    __syncthreads();
    s = ss[0] + ss[1] + ss[2] + ss[3];
    q = qq[0] + qq[1] + qq[2] + qq[3];
    float mu = s * (1.f / 256.f);
    float var = q * (1.f / 256.f) - mu * mu;
    float inv = rsqrtf(var + 1e-5f);
    h16[(size_t)row * 256 + t] = __float2half_rn((v - mu) * inv * g[t] + bv[t]);
    return;
  }
  int bx = blockIdx.x - 2048;
  if (bx < 768) {
    wqT[(size_t)bx * 256 + t] = __float2half_rn(w_qkv[(size_t)t * 768 + bx]);
  } else if (bx < 1024) {
    int n = bx - 768;
    woT[(size_t)n * 256 + t] = __float2half_rn(w_o[(size_t)t * 256 + n]);
  } else if (bx == 1024) {
#pragma unroll
    for (int s = 0; s < 8; s++) {
      int e = t * 8 + s;
      float z = -16.f + (float)e * (1.f / 64.f);
      float g0 = gelu_exact(z);
      float g1 = gelu_exact(z + (1.f / 64.f));
      gtabu[e] = packh2(g0, g1 - g0);
    }
  } else {
    if (t < 128) {
      int hb = t >> 6, l = t & 63;
      int hid = hb * 32 + (l & 31);
      float v[4];
#pragma unroll
      for (int e = 0; e < 4; e++) {
        int k = (l >> 5) * 4 + e;
        v[e] = (k < 5) ? w1[k * 64 + hid] : ((k == 5) ? b1[hid] : 0.f);
      }
      A1g[t] = make_uint2(packh2(v[0], v[1]), packh2(v[2], v[3]));
    }
    {
      int c = t >> 6, l = t & 63;
      int row = l & 31;
      int lh = l >> 5;
      float v[8];
#pragma unroll
      for (int e = 0; e < 8; e++) {
        int hid = c * 16 + (e & 3) + 8 * (e >> 2) + 4 * lh;
        v[e] = (row < 8) ? w2[hid * 8 + row] : 0.f;
      }
      A2g[t] = make_uint4(packh2(v[0], v[1]), packh2(v[2], v[3]),
                          packh2(v[4], v[5]), packh2(v[6], v[7]));
    }
  }
}

// ---------------------------------------------------------------------------
// QKV GEMM (32x32 MFMA tiles) with FUSED RoPE epilogue (R14-verified).
// Q is PRE-SCALED by 1/sqrt(32) so attention can use rel as the MFMA C-op.
// ---------------------------------------------------------------------------
__global__ __launch_bounds__(256) void qkv_rope(
    const __half* __restrict__ h16, const __half* __restrict__ wqT,
    __half* __restrict__ qo, __half* __restrict__ ko, __half* __restrict__ vo) {
  int wave = blockIdx.x * 4 + (threadIdx.x >> 6);  // 1536 waves: 64 mt x 24 nt
  int mt = wave / 24, nt = wave - mt * 24;
  int l = threadIdx.x & 63;
  int c31 = l & 31, kg = l >> 5;
  int m0 = mt * 32, n0 = nt * 32;
  floatx16 acc0 = {0.f}, acc1 = {0.f};
  const _Float16* ap = (const _Float16*)h16 + (size_t)(m0 + c31) * 256 + kg * 8;
  const _Float16* bp = (const _Float16*)wqT + (size_t)(n0 + c31) * 256 + kg * 8;
  for (int k0 = 0; k0 < 256; k0 += 32) {
    half8 a0 = *(const half8*)(ap + k0);
    half8 b0 = *(const half8*)(bp + k0);
    half8 a1 = *(const half8*)(ap + k0 + 16);
    half8 b1 = *(const half8*)(bp + k0 + 16);
    acc0 = MFMA_S2(a0, b0, acc0);
    acc1 = MFMA_S2(a1, b1, acc1);
  }
  floatx16 acc = acc0 + acc1;

  if (nt < 16) {
    __half* dst = (nt < 8) ? qo : ko;
    float qscale = (nt < 8) ? 0.17677669529663687f : 1.0f;
    int hh = nt & 7;
    int f = c31 & 15;
    float inv_freq = exp2f((float)f * -0.8304820237218407f);  // 10000^(-f/16)
#pragma unroll
    for (int r = 0; r < 16; r++) {
      float part = __shfl_xor(acc[r], 16);
      int m = m0 + (r & 3) + 8 * (r >> 2) + 4 * kg;
      int nseq = m & 1023, bb = m >> 10;
      float sn, cs;
      __sincosf((float)nseq * inv_freq, &sn, &cs);
      float out = (c31 < 16) ? (acc[r] * cs - part * sn)
                             : (acc[r] * cs + part * sn);
      dst[((size_t)(bb * 8 + hh) * 1024 + nseq) * 32 + c31] =
          __float2half_rn(out * qscale);
    }
  } else {
    int hh = nt - 16;
#pragma unroll
    for (int r = 0; r < 16; r++) {
      int m = m0 + (r & 3) + 8 * (r >> 2) + 4 * kg;
      int nseq = m & 1023, bb = m >> 10;
      vo[((size_t)(bb * 8 + hh) * 1024 + nseq) * 32 + c31] = __float2half_rn(acc[r]);
    }
  }
}

// ---------------------------------------------------------------------------
// Table GELU, f16 lerp: 4B half2{g0,dg} entries, step 1/64 on [-16,16).
// ---------------------------------------------------------------------------
__device__ __forceinline__ _Float16 gelu_tab16(float z, const unsigned int* gt) {
  float tf = __builtin_amdgcn_fmed3f(fmaf(z, 64.f, 1024.f), 0.f, 2047.f);
  float fr = __builtin_amdgcn_fractf(tf);
  unsigned int e = gt[(unsigned int)tf];
  union { unsigned int u; _Float16 h[2]; } cv;
  cv.u = e;
  return (_Float16)(cv.h[0] + (_Float16)fr * cv.h[1]);
}

// ---------------------------------------------------------------------------
// FUSED rel-MLP + flash attention, SOFTWARE-PIPELINED:
//   A(0) -> bar -> { A(1) || B(0) } -> bar -> B(1)
// relS double-buffered (2 x [8][64][18] f16). Block = (b, i-tile 16,
// j-eighth 128), 512 thr = 8 waves (wave = head). Phase math R11/R14-verified;
// rel enters QK^T as the MFMA C-operand (Q pre-scaled by 1/sqrt(32)).
// ---------------------------------------------------------------------------
__global__ __launch_bounds__(512) void fused_attn(
    const __half* __restrict__ qh, const __half* __restrict__ kh,
    const __half* __restrict__ vh,
    const float* __restrict__ coords, const float* __restrict__ vels,
    const unsigned int* __restrict__ gtabu, const uint2* __restrict__ A1g,
    const uint4* __restrict__ A2g, const float* __restrict__ b2,
    float* __restrict__ Opart, float* __restrict__ ml) {
  __shared__ unsigned int gtab[2048];
  __shared__ __half relS[2][8][64][18];
  const int t = threadIdx.x;
  for (int e = t; e < 2048; e += 512) gtab[e] = gtabu[e];

  const int js = blockIdx.x & 7;
  const int it = (blockIdx.x >> 3) & 63;
  const int b  = blockIdx.x >> 9;
  const int h  = t >> 6;           // wave index = head
  const int lane = t & 63;
  const int lg = lane >> 4, li16 = lane & 15;
  const int li = lane & 31, lh = lane >> 5;
  const int i0 = it * 16;
  const size_t bh = (size_t)(b * 8 + h) * 1024;

  float b2v0 = b2[4 * lh + 0], b2v1 = b2[4 * lh + 1];
  float b2v2 = b2[4 * lh + 2], b2v3 = b2[4 * lh + 3];

  const half8 qf = *(const half8*)((const _Float16*)qh + (bh + i0 + li16) * 32 + 8 * lg);
  floatx4 accLo = {0.f, 0.f, 0.f, 0.f};
  floatx4 accHi = {0.f, 0.f, 0.f, 0.f};
  float m_run = -3.0e38f, l_run = 0.f;

  uint2 a1u0 = A1g[lane], a1u1 = A1g[64 + lane];
  uint4 a2u0 = A2g[lane], a2u1 = A2g[64 + lane];
  uint4 a2u2 = A2g[128 + lane], a2u3 = A2g[192 + lane];

  // ---- phase A for chunk `c` into relS[buf] ----
#define PHASE_A(CHUNK, BUF)                                                    \
  {                                                                            \
    const int jtA = js * 128 + (CHUNK) * 64;                                   \
    _Pragma("unroll")                                                          \
    for (int tt = 0; tt < 4; tt++) {                                           \
      const int i_loc = 2 * h + (tt >> 1);                                     \
      const int jsub = tt & 1;                                                 \
      const int iA = i0 + i_loc;                                               \
      const int jA = jtA + jsub * 32 + li;                                     \
      float2 ci = *(const float2*)&coords[(size_t)(b * 1024 + iA) * 2];        \
      float2 vi = *(const float2*)&vels[(size_t)(b * 1024 + iA) * 2];          \
      float2 cj = *(const float2*)&coords[(size_t)(b * 1024 + jA) * 2];        \
      float2 vj = *(const float2*)&vels[(size_t)(b * 1024 + jA) * 2];          \
      float dx0 = ci.x - cj.x, dx1 = ci.y - cj.y;                              \
      float dv0 = vi.x - vj.x, dv1 = vi.y - vj.y;                              \
      float dist = sqrtf(dx0 * dx0 + dx1 * dx1);                               \
      half4 bf;                                                                \
      bf[0] = lh ? (_Float16)dv1 : (_Float16)dx0;                              \
      bf[1] = lh ? (_Float16)1.0f : (_Float16)dx1;                             \
      bf[2] = lh ? (_Float16)0.0f : (_Float16)dist;                            \
      bf[3] = lh ? (_Float16)0.0f : (_Float16)dv0;                             \
      floatx16 zinit = {0.f};                                                  \
      floatx16 acc = {0.f};                                                    \
      {                                                                        \
        floatx16 z0 = MFMA_S1(*(half4*)&a1u0, bf, zinit);                      \
        unsigned int u[8] __attribute__((aligned(16)));                        \
        _Pragma("unroll")                                                      \
        for (int q = 0; q < 8; q++) {                                          \
          _Float16 ga = gelu_tab16(z0[2 * q], gtab);                           \
          _Float16 gb = gelu_tab16(z0[2 * q + 1], gtab);                       \
          union { unsigned int uu; _Float16 hx[2]; } cv;                       \
          cv.hx[0] = ga; cv.hx[1] = gb;                                        \
          u[q] = cv.uu;                                                        \
        }                                                                      \
        acc = MFMA_S2(*(half8*)&a2u0, *(half8*)&u[0], acc);                    \
        acc = MFMA_S2(*(half8*)&a2u1, *(half8*)&u[4], acc);                    \
      }                                                                        \
      {                                                                        \
        floatx16 z1 = MFMA_S1(*(half4*)&a1u1, bf, zinit);                      \
        unsigned int u[8] __attribute__((aligned(16)));                        \
        _Pragma("unroll")                                                      \
        for (int q = 0; q < 8; q++) {                                          \
          _Float16 ga = gelu_tab16(z1[2 * q], gtab);                           \
          _Float16 gb = gelu_tab16(z1[2 * q + 1], gtab);                       \
          union { unsigned int uu; _Float16 hx[2]; } cv;                       \
          cv.hx[0] = ga; cv.hx[1] = gb;                                        \
          u[q] = cv.uu;                                                        \
        }                                                                      \
        acc = MFMA_S2(*(half8*)&a2u2, *(half8*)&u[0], acc);                    \
        acc = MFMA_S2(*(half8*)&a2u3, *(half8*)&u[4], acc);                    \
      }                                                                        \
      const int jc = jsub * 32 + li;                                           \
      relS[BUF][4 * lh + 0][jc][i_loc] = __float2half_rn(acc[0] + b2v0);       \
      relS[BUF][4 * lh + 1][jc][i_loc] = __float2half_rn(acc[1] + b2v1);       \
      relS[BUF][4 * lh + 2][jc][i_loc] = __float2half_rn(acc[2] + b2v2);       \
      relS[BUF][4 * lh + 3][jc][i_loc] = __float2half_rn(acc[3] + b2v3);       \
    }                                                                          \
  }

  // ---- phase B for chunk `c` from relS[buf] ----
#define PHASE_B(CHUNK, BUF)                                                    \
  {                                                                            \
    const int jtB = js * 128 + (CHUNK) * 64;                                   \
    const _Float16* kb = (const _Float16*)kh + (bh + jtB + li16) * 32 + 8 * lg;\
    half8 kf0 = *(const half8*)(kb + 0 * 512);                                 \
    half8 kf1 = *(const half8*)(kb + 1 * 512);                                 \
    half8 kf2 = *(const half8*)(kb + 2 * 512);                                 \
    half8 kf3 = *(const half8*)(kb + 3 * 512);                                 \
    floatx4 c0, c1, c2, c3;                                                    \
    _Pragma("unroll")                                                          \
    for (int r = 0; r < 4; r++) {                                              \
      c0[r] = __half2float(relS[BUF][h][0 + 4 * lg + r][li16]);                \
      c1[r] = __half2float(relS[BUF][h][16 + 4 * lg + r][li16]);               \
      c2[r] = __half2float(relS[BUF][h][32 + 4 * lg + r][li16]);               \
      c3[r] = __half2float(relS[BUF][h][48 + 4 * lg + r][li16]);               \
    }                                                                          \
    __builtin_amdgcn_s_setprio(1);                                             \
    floatx4 st0 = __builtin_amdgcn_mfma_f32_16x16x32_f16(kf0, qf, c0, 0, 0, 0);\
    floatx4 st1 = __builtin_amdgcn_mfma_f32_16x16x32_f16(kf1, qf, c1, 0, 0, 0);\
    floatx4 st2 = __builtin_amdgcn_mfma_f32_16x16x32_f16(kf2, qf, c2, 0, 0, 0);\
    floatx4 st3 = __builtin_amdgcn_mfma_f32_16x16x32_f16(kf3, qf, c3, 0, 0, 0);\
    __builtin_amdgcn_s_setprio(0);                                             \
    float s[16];                                                               \
    _Pragma("unroll")                                                          \
    for (int r = 0; r < 4; r++) {                                              \
      s[0 + r] = st0[r]; s[4 + r] = st1[r];                                    \
      s[8 + r] = st2[r]; s[12 + r] = st3[r];                                   \
    }                                                                          \
    float tm = fmaxf(fmaxf(fmaxf(s[0], s[1]), fmaxf(s[2], s[3])),              \
                     fmaxf(fmaxf(s[4], s[5]), fmaxf(s[6], s[7])));             \
    tm = fmaxf(tm, fmaxf(fmaxf(fmaxf(s[8], s[9]), fmaxf(s[10], s[11])),        \
                         fmaxf(fmaxf(s[12], s[13]), fmaxf(s[14], s[15]))));    \
    tm = fmaxf(tm, __shfl_xor(tm, 16));                                        \
    tm = fmaxf(tm, __shfl_xor(tm, 32));                                        \
    float nm = fmaxf(m_run, tm);                                               \
    float fc = __expf(m_run - nm);                                             \
    float p[16];                                                               \
    _Pragma("unroll")                                                          \
    for (int e = 0; e < 16; e++) p[e] = __expf(s[e] - nm);                     \
    float ts = ((p[0] + p[1]) + (p[2] + p[3])) + ((p[4] + p[5]) + (p[6] + p[7]));\
    ts += ((p[8] + p[9]) + (p[10] + p[11])) + ((p[12] + p[13]) + (p[14] + p[15]));\
    ts += __shfl_xor(ts, 16);                                                  \
    ts += __shfl_xor(ts, 32);                                                  \
    l_run = l_run * fc + ts;                                                   \
    m_run = nm;                                                                \
    float fT0 = __shfl(fc, 4 * lg + 0);                                        \
    float fT1 = __shfl(fc, 4 * lg + 1);                                        \
    float fT2 = __shfl(fc, 4 * lg + 2);                                        \
    float fT3 = __shfl(fc, 4 * lg + 3);                                        \
    accLo[0] *= fT0; accHi[0] *= fT0;                                          \
    accLo[1] *= fT1; accHi[1] *= fT1;                                          \
    accLo[2] *= fT2; accHi[2] *= fT2;                                          \
    accLo[3] *= fT3; accHi[3] *= fT3;                                          \
    _Pragma("unroll")                                                          \
    for (int tt = 0; tt < 4; tt++) {                                           \
      half4 pf;                                                                \
      pf[0] = (_Float16)p[4 * tt + 0];                                         \
      pf[1] = (_Float16)p[4 * tt + 1];                                         \
      pf[2] = (_Float16)p[4 * tt + 2];                                         \
      pf[3] = (_Float16)p[4 * tt + 3];                                         \
      const _Float16* vb = (const _Float16*)vh + (bh + jtB + tt * 16 + 4 * lg) * 32 + li16;\
      half4 vf0, vf1;                                                          \
      vf0[0] = vb[0];  vf0[1] = vb[32]; vf0[2] = vb[64]; vf0[3] = vb[96];      \
      vf1[0] = vb[16]; vf1[1] = vb[48]; vf1[2] = vb[80]; vf1[3] = vb[112];     \
      __builtin_amdgcn_s_setprio(1);                                           \
      accLo = MFMA_PV(pf, vf0, accLo);                                         \
      accHi = MFMA_PV(pf, vf1, accHi);                                         \
      __builtin_amdgcn_s_setprio(0);                                           \
    }                                                                          \
  }

  __syncthreads();   // gtab ready
  PHASE_A(0, 0)
  __syncthreads();   // relS[0] ready
  PHASE_A(1, 1)      // overlaps (ILP + inter-wave) with...
  PHASE_B(0, 0)      // ...attention on chunk 0
  __syncthreads();   // relS[1] ready
  PHASE_B(1, 1)
#undef PHASE_A
#undef PHASE_B

  size_t orow = (size_t)(b * 8 + js) * 1024 + i0 + 4 * lg;
#pragma unroll
  for (int r = 0; r < 4; r++) {
    float* op = Opart + (orow + r) * 256 + h * 32 + li16;
    op[0] = accLo[r];
    op[16] = accHi[r];
  }
  if (lane < 16) {
    ((float2*)ml)[((size_t)(b * 8 + js) * 1024 + i0 + lane) * 8 + h] =
        make_float2(m_run, l_run);
  }
}

// ---------------------------------------------------------------------------
// FUSED combine + out-projection (R18-verified): grid = 256 blocks x 8 rows.
// ---------------------------------------------------------------------------
__global__ __launch_bounds__(256) void combine_proj(
    const float* __restrict__ Opart, const float* __restrict__ ml,
    const __half* __restrict__ woT, const float* __restrict__ b_o,
    float* __restrict__ out) {
  __shared__ _Float16 As[16][264];
  const int r0 = blockIdx.x * 8;
  const int t = threadIdx.x;
  const int hh = t >> 5;
#pragma unroll
  for (int rr = 8; rr < 16; rr++) As[rr][t] = (_Float16)0.f;
#pragma unroll
  for (int rr = 0; rr < 8; rr++) {
    int row = r0 + rr;
    int b = row >> 10, i = row & 1023;
    float2 mls[8];
    float M = -1e30f;
#pragma unroll
    for (int js = 0; js < 8; js++) {
      mls[js] = ((const float2*)ml)[(((size_t)(b * 8 + js) * 1024) + i) * 8 + hh];
      M = fmaxf(M, mls[js].x);
    }
    float L = 0.f, Ov = 0.f;
#pragma unroll
    for (int js = 0; js < 8; js++) {
      float w = __expf(mls[js].x - M);
      L += mls[js].y * w;
      Ov += Opart[(((size_t)(b * 8 + js) * 1024) + i) * 256 + t] * w;
    }
    As[rr][t] = (_Float16)(Ov / L);
  }
  __syncthreads();
  const int wv = t >> 6, lane = t & 63;
  const int lg = lane >> 4, li = lane & 15;
#pragma unroll
  for (int nt = 0; nt < 4; nt++) {
    int n0 = (wv * 4 + nt) * 16;
    floatx4 acc = {0.f, 0.f, 0.f, 0.f};
    const _Float16* bp = (const _Float16*)woT + (size_t)(n0 + li) * 256 + 8 * lg;
#pragma unroll
    for (int k0 = 0; k0 < 256; k0 += 32) {
      half8 af = *(const half8*)&As[li][k0 + 8 * lg];
      half8 bf = *(const half8*)(bp + k0);
      acc = __builtin_amdgcn_mfma_f32_16x16x32_f16(af, bf, acc, 0, 0, 0);
    }
    float bb = b_o[n0 + li];
#pragma unroll
    for (int r = 0; r < 4; r++) {
      int mrow = 4 * lg + r;
      if (mrow < 8) out[(size_t)(r0 + mrow) * 256 + n0 + li] = acc[r] + bb;
    }
  }
}

// ---------------------------------------------------------------------------
extern "C" void kernel_launch(void* const* d_in, const int* in_sizes, int n_in,
                              void* d_out, int out_size, void* d_ws, size_t ws_size,
                              hipStream_t stream) {
  const float* x      = (const float*)d_in[0];
  const float* coords = (const float*)d_in[1];
  const float* vels   = (const float*)d_in[2];
  const float* ln_g   = (const float*)d_in[3];
  const float* ln_b   = (const float*)d_in[4];
  const float* w_qkv  = (const float*)d_in[5];
  const float* w_o    = (const float*)d_in[6];
  const float* b_o    = (const float*)d_in[7];
  const float* w1     = (const float*)d_in[8];
  const float* b1     = (const float*)d_in[9];
  const float* w2     = (const float*)d_in[10];
  const float* b2     = (const float*)d_in[11];
  float* out = (float*)d_out;

  // ws layout (bytes):
  //  [0, 16Mi)      Opart f32 (8 j-splits x 2048 rows x 256)
  //  [16Mi, +545KB) wqT f16 | woT f16 | gtab(u32) | A1 | A2
  //  [17Mi, 18Mi)   h16 (ln out; dead after qkv_rope)
  //  [18Mi,19Mi) qh  [19Mi,20Mi) kh  [20Mi,21Mi) vh
  //  [21Mi, 22Mi)   ml (float2 per (b,js,i,h))
  char* wsb = (char*)d_ws;
  float* Opart = (float*)wsb;
  __half* wqT  = (__half*)(wsb + 16777216);
  __half* woT  = (__half*)(wsb + 17170432);
  unsigned int* gtab = (unsigned int*)(wsb + 17301504);
  uint2* A1g   = (uint2*)(wsb + 17317888);
  uint4* A2g   = (uint4*)(wsb + 17318912);
  __half* h16  = (__half*)(wsb + 17825792);
  __half* qh   = (__half*)(wsb + 18874368);
  __half* kh   = (__half*)(wsb + 19922944);
  __half* vh   = (__half*)(wsb + 20971520);
  float* ml    = (float*)(wsb + 22020096);

  prep_kernel<<<3074, 256, 0, stream>>>(x, ln_g, ln_b, h16, w_qkv, w_o,
                                        w1, b1, w2, wqT, woT, gtab, A1g, A2g);
  qkv_rope<<<384, 256, 0, stream>>>(h16, wqT, qh, kh, vh);
  fused_attn<<<1024, 512, 0, stream>>>(qh, kh, vh, coords, vels, gtab,
                                       A1g, A2g, b2, Opart, ml);
  combine_proj<<<256, 256, 0, stream>>>(Opart, ml, woT, b_o, out);
}

// Round 20
// 75.468 us; speedup vs baseline: 1.0751x; 1.0751x over previous
//
#include <hip/hip_runtime.h>
#include <hip/hip_bf16.h>
#include <hip/hip_fp16.h>
#include <math.h>
#include <string.h>

typedef _Float16 half8 __attribute__((ext_vector_type(8)));
typedef _Float16 half4 __attribute__((ext_vector_type(4)));
typedef float floatx4 __attribute__((ext_vector_type(4)));
typedef float floatx16 __attribute__((ext_vector_type(16)));

#if defined(__has_builtin) && __has_builtin(__builtin_amdgcn_mfma_f32_16x16x16f16)
#define MFMA_PV(a, b, c) __builtin_amdgcn_mfma_f32_16x16x16f16((a), (b), (c), 0, 0, 0)
#else
__device__ __forceinline__ floatx4 mfma_pv_asm(half4 a, half4 b, floatx4 c) {
  floatx4 d;
  asm volatile("v_mfma_f32_16x16x16_f16 %0, %1, %2, %3"
               : "=v"(d) : "v"(a), "v"(b), "v"(c));
  return d;
}
#define MFMA_PV(a, b, c) mfma_pv_asm((a), (b), (c))
#endif

__device__ __forceinline__ floatx16 MFMA_S1(half4 a, half4 b, floatx16 c) {
#if defined(__has_builtin) && __has_builtin(__builtin_amdgcn_mfma_f32_32x32x8f16)
  return __builtin_amdgcn_mfma_f32_32x32x8f16(a, b, c, 0, 0, 0);
#else
  floatx16 d;
  asm volatile("v_mfma_f32_32x32x8_f16 %0, %1, %2, %3"
               : "=v"(d) : "v"(a), "v"(b), "v"(c));
  return d;
#endif
}

__device__ __forceinline__ floatx16 MFMA_S2(half8 a, half8 b, floatx16 c) {
#if defined(__has_builtin) && __has_builtin(__builtin_amdgcn_mfma_f32_32x32x16_f16)
  return __builtin_amdgcn_mfma_f32_32x32x16_f16(a, b, c, 0, 0, 0);
#else
  floatx16 d;
  asm volatile("v_mfma_f32_32x32x16_f16 %0, %1, %2, %3"
               : "=v"(d) : "v"(a), "v"(b), "v"(c));
  return d;
#endif
}

__device__ __forceinline__ float gelu_exact(float z) {
  return 0.5f * z * (1.0f + erff(z * 0.70710678118654752f));
}
__device__ __forceinline__ unsigned int packh2(float a, float b) {
  __half2 h = __halves2half2(__float2half_rn(a), __float2half_rn(b));
  unsigned int u;
  memcpy(&u, &h, 4);
  return u;
}

// ---------------------------------------------------------------------------
// Fused prep: bx<2048 -> LayerNorm row (f16); else weight transpose, the
// 8192-entry f16 NEAREST GELU table (step 1/256 on [-16,16)), MFMA frags.
// ---------------------------------------------------------------------------
__global__ __launch_bounds__(256) void prep_kernel(
    const float* __restrict__ x, const float* __restrict__ g,
    const float* __restrict__ bv, __half* __restrict__ h16,
    const float* __restrict__ w_qkv, const float* __restrict__ w_o,
    const float* __restrict__ w1, const float* __restrict__ b1,
    const float* __restrict__ w2,
    __half* __restrict__ wqT, __half* __restrict__ woT,
    __half* __restrict__ gtabh, uint2* __restrict__ A1g,
    uint4* __restrict__ A2g) {
  int t = threadIdx.x;
  if (blockIdx.x < 2048) {
    int row = blockIdx.x;
    float v = x[(size_t)row * 256 + t];
    float s = v, q = v * v;
#pragma unroll
    for (int o = 32; o > 0; o >>= 1) {
      s += __shfl_xor(s, o);
      q += __shfl_xor(q, o);
    }
    __shared__ float ss[4], qq[4];
    int w = t >> 6, l = t & 63;
    if (l == 0) { ss[w] = s; qq[w] = q; }
    __syncthreads();
    s = ss[0] + ss[1] + ss[2] + ss[3];
    q = qq[0] + qq[1] + qq[2] + qq[3];
    float mu = s * (1.f / 256.f);
    float var = q * (1.f / 256.f) - mu * mu;
    float inv = rsqrtf(var + 1e-5f);
    h16[(size_t)row * 256 + t] = __float2half_rn((v - mu) * inv * g[t] + bv[t]);
    return;
  }
  int bx = blockIdx.x - 2048;
  if (bx < 768) {
    wqT[(size_t)bx * 256 + t] = __float2half_rn(w_qkv[(size_t)t * 768 + bx]);
  } else if (bx < 1024) {
    int n = bx - 768;
    woT[(size_t)n * 256 + t] = __float2half_rn(w_o[(size_t)t * 256 + n]);
  } else if (bx == 1024) {
#pragma unroll
    for (int s = 0; s < 32; s++) {
      int e = t * 32 + s;
      float z = -16.f + (float)e * (1.f / 256.f);
      gtabh[e] = __float2half_rn(gelu_exact(z));
    }
  } else {
    if (t < 128) {
      int hb = t >> 6, l = t & 63;
      int hid = hb * 32 + (l & 31);
      float v[4];
#pragma unroll
      for (int e = 0; e < 4; e++) {
        int k = (l >> 5) * 4 + e;
        v[e] = (k < 5) ? w1[k * 64 + hid] : ((k == 5) ? b1[hid] : 0.f);
      }
      A1g[t] = make_uint2(packh2(v[0], v[1]), packh2(v[2], v[3]));
    }
    {
      int c = t >> 6, l = t & 63;
      int row = l & 31;
      int lh = l >> 5;
      float v[8];
#pragma unroll
      for (int e = 0; e < 8; e++) {
        int hid = c * 16 + (e & 3) + 8 * (e >> 2) + 4 * lh;
        v[e] = (row < 8) ? w2[hid * 8 + row] : 0.f;
      }
      A2g[t] = make_uint4(packh2(v[0], v[1]), packh2(v[2], v[3]),
                          packh2(v[4], v[5]), packh2(v[6], v[7]));
    }
  }
}

// ---------------------------------------------------------------------------
// QKV GEMM (32x32 MFMA tiles) with FUSED RoPE epilogue (R14-verified).
// Q is PRE-SCALED by 1/sqrt(32) so attention can use rel as the MFMA C-op.
// ---------------------------------------------------------------------------
__global__ __launch_bounds__(256) void qkv_rope(
    const __half* __restrict__ h16, const __half* __restrict__ wqT,
    __half* __restrict__ qo, __half* __restrict__ ko, __half* __restrict__ vo) {
  int wave = blockIdx.x * 4 + (threadIdx.x >> 6);  // 1536 waves: 64 mt x 24 nt
  int mt = wave / 24, nt = wave - mt * 24;
  int l = threadIdx.x & 63;
  int c31 = l & 31, kg = l >> 5;
  int m0 = mt * 32, n0 = nt * 32;
  floatx16 acc0 = {0.f}, acc1 = {0.f};
  const _Float16* ap = (const _Float16*)h16 + (size_t)(m0 + c31) * 256 + kg * 8;
  const _Float16* bp = (const _Float16*)wqT + (size_t)(n0 + c31) * 256 + kg * 8;
  for (int k0 = 0; k0 < 256; k0 += 32) {
    half8 a0 = *(const half8*)(ap + k0);
    half8 b0 = *(const half8*)(bp + k0);
    half8 a1 = *(const half8*)(ap + k0 + 16);
    half8 b1 = *(const half8*)(bp + k0 + 16);
    acc0 = MFMA_S2(a0, b0, acc0);
    acc1 = MFMA_S2(a1, b1, acc1);
  }
  floatx16 acc = acc0 + acc1;

  if (nt < 16) {
    __half* dst = (nt < 8) ? qo : ko;
    float qscale = (nt < 8) ? 0.17677669529663687f : 1.0f;
    int hh = nt & 7;
    int f = c31 & 15;
    float inv_freq = exp2f((float)f * -0.8304820237218407f);  // 10000^(-f/16)
#pragma unroll
    for (int r = 0; r < 16; r++) {
      float part = __shfl_xor(acc[r], 16);
      int m = m0 + (r & 3) + 8 * (r >> 2) + 4 * kg;
      int nseq = m & 1023, bb = m >> 10;
      float sn, cs;
      __sincosf((float)nseq * inv_freq, &sn, &cs);
      float out = (c31 < 16) ? (acc[r] * cs - part * sn)
                             : (acc[r] * cs + part * sn);
      dst[((size_t)(bb * 8 + hh) * 1024 + nseq) * 32 + c31] =
          __float2half_rn(out * qscale);
    }
  } else {
    int hh = nt - 16;
#pragma unroll
    for (int r = 0; r < 16; r++) {
      int m = m0 + (r & 3) + 8 * (r >> 2) + 4 * kg;
      int nseq = m & 1023, bb = m >> 10;
      vo[((size_t)(bb * 8 + hh) * 1024 + nseq) * 32 + c31] = __float2half_rn(acc[r]);
    }
  }
}

// ---------------------------------------------------------------------------
// NEAREST table GELU: idx = round(z*256)+4096 clamped; 1 ds_read_u16, no lerp.
// ---------------------------------------------------------------------------
__device__ __forceinline__ _Float16 gelu_near16(float z, const _Float16* gt) {
  float tf = __builtin_amdgcn_fmed3f(fmaf(z, 256.f, 4096.5f), 0.f, 8191.f);
  return gt[(unsigned int)tf];
}

// ---------------------------------------------------------------------------
// FUSED rel-MLP + flash attention (R18-verified sequential structure).
// Block = (b, i-tile 16, j-eighth 128), 512 thr = 8 waves (wave = head).
// Per 64-j chunk: phase A (MLP via MFMA + nearest-table GELU -> relS LDS);
// bar; phase B (QK with rel as C-op + softmax + PV); bar.
// ---------------------------------------------------------------------------
__global__ __launch_bounds__(512) void fused_attn(
    const __half* __restrict__ qh, const __half* __restrict__ kh,
    const __half* __restrict__ vh,
    const float* __restrict__ coords, const float* __restrict__ vels,
    const __half* __restrict__ gtabh, const uint2* __restrict__ A1g,
    const uint4* __restrict__ A2g, const float* __restrict__ b2,
    float* __restrict__ Opart, float* __restrict__ ml) {
  __shared__ unsigned int gt32[4096];   // 8192 f16 entries
  __shared__ __half relS[8][64][18];
  const int t = threadIdx.x;
  {
    const unsigned int* gsrc = (const unsigned int*)gtabh;
    for (int e = t; e < 4096; e += 512) gt32[e] = gsrc[e];
  }
  const _Float16* gtab = (const _Float16*)gt32;

  const int js = blockIdx.x & 7;
  const int it = (blockIdx.x >> 3) & 63;
  const int b  = blockIdx.x >> 9;
  const int h  = t >> 6;           // wave index = head
  const int lane = t & 63;
  const int lg = lane >> 4, li16 = lane & 15;
  const int li = lane & 31, lh = lane >> 5;
  const int i0 = it * 16;
  const size_t bh = (size_t)(b * 8 + h) * 1024;

  float b2v0 = b2[4 * lh + 0], b2v1 = b2[4 * lh + 1];
  float b2v2 = b2[4 * lh + 2], b2v3 = b2[4 * lh + 3];

  const half8 qf = *(const half8*)((const _Float16*)qh + (bh + i0 + li16) * 32 + 8 * lg);
  floatx4 accLo = {0.f, 0.f, 0.f, 0.f};
  floatx4 accHi = {0.f, 0.f, 0.f, 0.f};
  float m_run = -3.0e38f, l_run = 0.f;

  uint2 a1u0 = A1g[lane], a1u1 = A1g[64 + lane];
  uint4 a2u0 = A2g[lane], a2u1 = A2g[64 + lane];
  uint4 a2u2 = A2g[128 + lane], a2u3 = A2g[192 + lane];

  __syncthreads();  // gtab ready

  for (int chunk = 0; chunk < 2; chunk++) {
    const int jt = js * 128 + chunk * 64;
    // ============ phase A: MLP bias for 16 i x 64 j ============
    {
#pragma unroll
      for (int tt = 0; tt < 4; tt++) {
        const int i_loc = 2 * h + (tt >> 1);
        const int jsub = tt & 1;
        const int i = i0 + i_loc;
        const int j = jt + jsub * 32 + li;
        float2 ci = *(const float2*)&coords[(size_t)(b * 1024 + i) * 2];
        float2 vi = *(const float2*)&vels[(size_t)(b * 1024 + i) * 2];
        float2 cj = *(const float2*)&coords[(size_t)(b * 1024 + j) * 2];
        float2 vj = *(const float2*)&vels[(size_t)(b * 1024 + j) * 2];
        float dx0 = ci.x - cj.x, dx1 = ci.y - cj.y;
        float dv0 = vi.x - vj.x, dv1 = vi.y - vj.y;
        float dist = sqrtf(dx0 * dx0 + dx1 * dx1);
        half4 bf;
        bf[0] = lh ? (_Float16)dv1 : (_Float16)dx0;
        bf[1] = lh ? (_Float16)1.0f : (_Float16)dx1;
        bf[2] = lh ? (_Float16)0.0f : (_Float16)dist;
        bf[3] = lh ? (_Float16)0.0f : (_Float16)dv0;

        floatx16 zinit = {0.f};
        floatx16 acc = {0.f};
        {
          floatx16 z0 = MFMA_S1(*(half4*)&a1u0, bf, zinit);
          unsigned int u[8] __attribute__((aligned(16)));
#pragma unroll
          for (int q = 0; q < 8; q++) {
            _Float16 ga = gelu_near16(z0[2 * q], gtab);
            _Float16 gb = gelu_near16(z0[2 * q + 1], gtab);
            union { unsigned int uu; _Float16 hx[2]; } cv;
            cv.hx[0] = ga; cv.hx[1] = gb;
            u[q] = cv.uu;
          }
          acc = MFMA_S2(*(half8*)&a2u0, *(half8*)&u[0], acc);
          acc = MFMA_S2(*(half8*)&a2u1, *(half8*)&u[4], acc);
        }
        {
          floatx16 z1 = MFMA_S1(*(half4*)&a1u1, bf, zinit);
          unsigned int u[8] __attribute__((aligned(16)));
#pragma unroll
          for (int q = 0; q < 8; q++) {
            _Float16 ga = gelu_near16(z1[2 * q], gtab);
            _Float16 gb = gelu_near16(z1[2 * q + 1], gtab);
            union { unsigned int uu; _Float16 hx[2]; } cv;
            cv.hx[0] = ga; cv.hx[1] = gb;
            u[q] = cv.uu;
          }
          acc = MFMA_S2(*(half8*)&a2u2, *(half8*)&u[0], acc);
          acc = MFMA_S2(*(half8*)&a2u3, *(half8*)&u[4], acc);
        }
        const int jc = jsub * 32 + li;
        relS[4 * lh + 0][jc][i_loc] = __float2half_rn(acc[0] + b2v0);
        relS[4 * lh + 1][jc][i_loc] = __float2half_rn(acc[1] + b2v1);
        relS[4 * lh + 2][jc][i_loc] = __float2half_rn(acc[2] + b2v2);
        relS[4 * lh + 3][jc][i_loc] = __float2half_rn(acc[3] + b2v3);
      }
    }
    __syncthreads();  // relS ready
    // ============ phase B: QK + softmax + PV for this 64-j chunk ============
    {
      const _Float16* kb = (const _Float16*)kh + (bh + jt + li16) * 32 + 8 * lg;
      half8 kf0 = *(const half8*)(kb + 0 * 512);
      half8 kf1 = *(const half8*)(kb + 1 * 512);
      half8 kf2 = *(const half8*)(kb + 2 * 512);
      half8 kf3 = *(const half8*)(kb + 3 * 512);
      // rel as C-operand (C/D layouts identical: row=j-loc, col=i)
      floatx4 c0, c1, c2, c3;
#pragma unroll
      for (int r = 0; r < 4; r++) {
        c0[r] = __half2float(relS[h][0 + 4 * lg + r][li16]);
        c1[r] = __half2float(relS[h][16 + 4 * lg + r][li16]);
        c2[r] = __half2float(relS[h][32 + 4 * lg + r][li16]);
        c3[r] = __half2float(relS[h][48 + 4 * lg + r][li16]);
      }
      __builtin_amdgcn_s_setprio(1);
      floatx4 st0 = __builtin_amdgcn_mfma_f32_16x16x32_f16(kf0, qf, c0, 0, 0, 0);
      floatx4 st1 = __builtin_amdgcn_mfma_f32_16x16x32_f16(kf1, qf, c1, 0, 0, 0);
      floatx4 st2 = __builtin_amdgcn_mfma_f32_16x16x32_f16(kf2, qf, c2, 0, 0, 0);
      floatx4 st3 = __builtin_amdgcn_mfma_f32_16x16x32_f16(kf3, qf, c3, 0, 0, 0);
      __builtin_amdgcn_s_setprio(0);
      float s[16];
#pragma unroll
      for (int r = 0; r < 4; r++) {
        s[0 + r] = st0[r]; s[4 + r] = st1[r];
        s[8 + r] = st2[r]; s[12 + r] = st3[r];
      }
      float tm = fmaxf(fmaxf(fmaxf(s[0], s[1]), fmaxf(s[2], s[3])),
                       fmaxf(fmaxf(s[4], s[5]), fmaxf(s[6], s[7])));
      tm = fmaxf(tm, fmaxf(fmaxf(fmaxf(s[8], s[9]), fmaxf(s[10], s[11])),
                           fmaxf(fmaxf(s[12], s[13]), fmaxf(s[14], s[15]))));
      tm = fmaxf(tm, __shfl_xor(tm, 16));
      tm = fmaxf(tm, __shfl_xor(tm, 32));
      float nm = fmaxf(m_run, tm);
      float fc = __expf(m_run - nm);
      float p[16];
#pragma unroll
      for (int e = 0; e < 16; e++) p[e] = __expf(s[e] - nm);
      float ts = ((p[0] + p[1]) + (p[2] + p[3])) + ((p[4] + p[5]) + (p[6] + p[7]));
      ts += ((p[8] + p[9]) + (p[10] + p[11])) + ((p[12] + p[13]) + (p[14] + p[15]));
      ts += __shfl_xor(ts, 16);
      ts += __shfl_xor(ts, 32);
      l_run = l_run * fc + ts;
      m_run = nm;
      float fT0 = __shfl(fc, 4 * lg + 0);
      float fT1 = __shfl(fc, 4 * lg + 1);
      float fT2 = __shfl(fc, 4 * lg + 2);
      float fT3 = __shfl(fc, 4 * lg + 3);
      accLo[0] *= fT0; accHi[0] *= fT0;
      accLo[1] *= fT1; accHi[1] *= fT1;
      accLo[2] *= fT2; accHi[2] *= fT2;
      accLo[3] *= fT3; accHi[3] *= fT3;
#pragma unroll
      for (int tt = 0; tt < 4; tt++) {
        half4 pf;
        pf[0] = (_Float16)p[4 * tt + 0];
        pf[1] = (_Float16)p[4 * tt + 1];
        pf[2] = (_Float16)p[4 * tt + 2];
        pf[3] = (_Float16)p[4 * tt + 3];
        const _Float16* vb = (const _Float16*)vh + (bh + jt + tt * 16 + 4 * lg) * 32 + li16;
        half4 vf0, vf1;
        vf0[0] = vb[0];  vf0[1] = vb[32]; vf0[2] = vb[64]; vf0[3] = vb[96];
        vf1[0] = vb[16]; vf1[1] = vb[48]; vf1[2] = vb[80]; vf1[3] = vb[112];
        __builtin_amdgcn_s_setprio(1);
        accLo = MFMA_PV(pf, vf0, accLo);
        accHi = MFMA_PV(pf, vf1, accHi);
        __builtin_amdgcn_s_setprio(0);
      }
    }
    __syncthreads();  // relS free for next chunk
  }
  size_t orow = (size_t)(b * 8 + js) * 1024 + i0 + 4 * lg;
#pragma unroll
  for (int r = 0; r < 4; r++) {
    float* op = Opart + (orow + r) * 256 + h * 32 + li16;
    op[0] = accLo[r];
    op[16] = accHi[r];
  }
  if (lane < 16) {
    ((float2*)ml)[((size_t)(b * 8 + js) * 1024 + i0 + lane) * 8 + h] =
        make_float2(m_run, l_run);
  }
}

// ---------------------------------------------------------------------------
// FUSED combine + out-projection (R18-verified): grid = 256 blocks x 8 rows.
// ---------------------------------------------------------------------------
__global__ __launch_bounds__(256) void combine_proj(
    const float* __restrict__ Opart, const float* __restrict__ ml,
    const __half* __restrict__ woT, const float* __restrict__ b_o,
    float* __restrict__ out) {
  __shared__ _Float16 As[16][264];
  const int r0 = blockIdx.x * 8;
  const int t = threadIdx.x;
  const int hh = t >> 5;
#pragma unroll
  for (int rr = 8; rr < 16; rr++) As[rr][t] = (_Float16)0.f;
#pragma unroll
  for (int rr = 0; rr < 8; rr++) {
    int row = r0 + rr;
    int b = row >> 10, i = row & 1023;
    float2 mls[8];
    float M = -1e30f;
#pragma unroll
    for (int js = 0; js < 8; js++) {
      mls[js] = ((const float2*)ml)[(((size_t)(b * 8 + js) * 1024) + i) * 8 + hh];
      M = fmaxf(M, mls[js].x);
    }
    float L = 0.f, Ov = 0.f;
#pragma unroll
    for (int js = 0; js < 8; js++) {
      float w = __expf(mls[js].x - M);
      L += mls[js].y * w;
      Ov += Opart[(((size_t)(b * 8 + js) * 1024) + i) * 256 + t] * w;
    }
    As[rr][t] = (_Float16)(Ov / L);
  }
  __syncthreads();
  const int wv = t >> 6, lane = t & 63;
  const int lg = lane >> 4, li = lane & 15;
#pragma unroll
  for (int nt = 0; nt < 4; nt++) {
    int n0 = (wv * 4 + nt) * 16;
    floatx4 acc = {0.f, 0.f, 0.f, 0.f};
    const _Float16* bp = (const _Float16*)woT + (size_t)(n0 + li) * 256 + 8 * lg;
#pragma unroll
    for (int k0 = 0; k0 < 256; k0 += 32) {
      half8 af = *(const half8*)&As[li][k0 + 8 * lg];
      half8 bf = *(const half8*)(bp + k0);
      acc = __builtin_amdgcn_mfma_f32_16x16x32_f16(af, bf, acc, 0, 0, 0);
    }
    float bb = b_o[n0 + li];
#pragma unroll
    for (int r = 0; r < 4; r++) {
      int mrow = 4 * lg + r;
      if (mrow < 8) out[(size_t)(r0 + mrow) * 256 + n0 + li] = acc[r] + bb;
    }
  }
}

// ---------------------------------------------------------------------------
extern "C" void kernel_launch(void* const* d_in, const int* in_sizes, int n_in,
                              void* d_out, int out_size, void* d_ws, size_t ws_size,
                              hipStream_t stream) {
  const float* x      = (const float*)d_in[0];
  const float* coords = (const float*)d_in[1];
  const float* vels   = (const float*)d_in[2];
  const float* ln_g   = (const float*)d_in[3];
  const float* ln_b   = (const float*)d_in[4];
  const float* w_qkv  = (const float*)d_in[5];
  const float* w_o    = (const float*)d_in[6];
  const float* b_o    = (const float*)d_in[7];
  const float* w1     = (const float*)d_in[8];
  const float* b1     = (const float*)d_in[9];
  const float* w2     = (const float*)d_in[10];
  const float* b2     = (const float*)d_in[11];
  float* out = (float*)d_out;

  // ws layout (bytes):
  //  [0, 16Mi)        Opart f32 (8 j-splits x 2048 rows x 256)
  //  [16Mi, +384Ki)   wqT f16
  //  [17170432, +128Ki) woT f16
  //  [17301504, +16Ki)  gtab f16 (8192 nearest entries)
  //  [17317888, +1Ki)   A1 frags ; [17318912, +4Ki) A2 frags
  //  [17825792, 18874368) h16 (dead after qkv_rope)
  //  [18Mi,19Mi) qh  [19Mi,20Mi) kh  [20Mi,21Mi) vh
  //  [21Mi, 22Mi)     ml (float2 per (b,js,i,h))
  char* wsb = (char*)d_ws;
  float* Opart = (float*)wsb;
  __half* wqT  = (__half*)(wsb + 16777216);
  __half* woT  = (__half*)(wsb + 17170432);
  __half* gtabh = (__half*)(wsb + 17301504);
  uint2* A1g   = (uint2*)(wsb + 17317888);
  uint4* A2g   = (uint4*)(wsb + 17318912);
  __half* h16  = (__half*)(wsb + 17825792);
  __half* qh   = (__half*)(wsb + 18874368);
  __half* kh   = (__half*)(wsb + 19922944);
  __half* vh   = (__half*)(wsb + 20971520);
  float* ml    = (float*)(wsb + 22020096);

  prep_kernel<<<3074, 256, 0, stream>>>(x, ln_g, ln_b, h16, w_qkv, w_o,
                                        w1, b1, w2, wqT, woT, gtabh, A1g, A2g);
  qkv_rope<<<384, 256, 0, stream>>>(h16, wqT, qh, kh, vh);
  fused_attn<<<1024, 512, 0, stream>>>(qh, kh, vh, coords, vels, gtabh,
                                       A1g, A2g, b2, Opart, ml);
  combine_proj<<<256, 256, 0, stream>>>(Opart, ml, woT, b_o, out);
}